// Round 1
// baseline (906.598 us; speedup 1.0000x reference)
//
#include <hip/hip_runtime.h>

#define NN 100000     // num nodes
#define NE 1600000    // num edges
#define NEL 200000    // link-pred edges
#define INC 64
#define POSC 16
#define HID 64
#define OUTC 32

// ---------------- degree / norm ----------------
__global__ void k_init_deg(float* __restrict__ deg) {
    int i = blockIdx.x * blockDim.x + threadIdx.x;
    if (i < NN) deg[i] = 1.0f;   // self-loop contributes 1
}

__global__ void k_count_deg(const int* __restrict__ dst, float* __restrict__ deg) {
    int i = blockIdx.x * blockDim.x + threadIdx.x;
    if (i < NE) atomicAdd(&deg[dst[i]], 1.0f);
}

__global__ void k_rsqrt(float* __restrict__ deg) {
    int i = blockIdx.x * blockDim.x + threadIdx.x;
    if (i < NN) deg[i] = rsqrtf(deg[i]);   // deg >= 1 always (self-loop)
}

// ---------------- hw1 = [x | pos] @ W1  (80 -> 64) ----------------
// One wave per node; lane j computes output channel j.
__global__ __launch_bounds__(256) void k_hw1(const float* __restrict__ x,
                                             const float* __restrict__ pos,
                                             const float* __restrict__ W1,
                                             float* __restrict__ hw1) {
    __shared__ float w[80 * 64];
    for (int t = threadIdx.x; t < 80 * 64; t += 256) w[t] = W1[t];
    __syncthreads();
    int lane = threadIdx.x & 63;
    int wave = threadIdx.x >> 6;
    int node = blockIdx.x * 4 + wave;          // grid = NN/4 exactly
    float hx = x[node * 64 + lane];
    float hp = (lane < 16) ? pos[node * 16 + lane] : 0.0f;
    float acc = 0.0f;
#pragma unroll 8
    for (int k = 0; k < 64; ++k)
        acc += __shfl(hx, k, 64) * w[k * 64 + lane];
#pragma unroll
    for (int k = 0; k < 16; ++k)
        acc += __shfl(hp, k, 64) * w[(64 + k) * 64 + lane];
    hw1[node * 64 + lane] = acc;
}

// ---------------- aggregator init: agg = hw * dinv^2 (self-loop term) ------
__global__ void k_init_agg(const float* __restrict__ hw, const float* __restrict__ dinv,
                           float* __restrict__ agg, int total, int shift) {
    int t = blockIdx.x * blockDim.x + threadIdx.x;
    if (t < total) {
        float di = dinv[t >> shift];
        agg[t] = hw[t] * di * di;
    }
}

// ---------------- edge scatter: agg[d] += hw[s] * dinv[s]*dinv[d] ----------
template <int C>
__global__ __launch_bounds__(256) void k_scatter(const int* __restrict__ src,
                                                 const int* __restrict__ dst,
                                                 const float* __restrict__ dinv,
                                                 const float* __restrict__ hw,
                                                 float* __restrict__ agg) {
    int t = blockIdx.x * blockDim.x + threadIdx.x;
    int lane = t & (C - 1);
    int e = t / C;
    int estride = (gridDim.x * blockDim.x) / C;
    for (; e < NE; e += estride) {
        int s = src[e], d = dst[e];
        float nrm = dinv[s] * dinv[d];
        atomicAdd(&agg[d * C + lane], hw[s * C + lane] * nrm);
    }
}

// ---------------- bias (+ optional relu), in place ----------------
__global__ void k_bias_relu(float* __restrict__ a, const float* __restrict__ b,
                            int total, int mask, int do_relu) {
    int t = blockIdx.x * blockDim.x + threadIdx.x;
    if (t < total) {
        float v = a[t] + b[t & mask];
        a[t] = do_relu ? fmaxf(v, 0.0f) : v;
    }
}

// ---------------- hw2 = h2 @ W2  (64 -> 32) ----------------
// One wave per 2 nodes: lanes 0-31 -> node a, lanes 32-63 -> node b.
__global__ __launch_bounds__(256) void k_hw2(const float* __restrict__ h,
                                             const float* __restrict__ W2,
                                             float* __restrict__ hw2) {
    __shared__ float w[64 * 32];
    for (int t = threadIdx.x; t < 64 * 32; t += 256) w[t] = W2[t];
    __syncthreads();
    int lane = threadIdx.x & 63;
    int wave = threadIdx.x >> 6;
    int j = lane & 31;
    int half = lane >> 5;
    int node = (blockIdx.x * 4 + wave) * 2 + half;   // grid = NN/8 exactly
    float hlo = h[node * 64 + j];
    float hhi = h[node * 64 + 32 + j];
    float acc = 0.0f;
    int base = half << 5;
#pragma unroll 8
    for (int k = 0; k < 32; ++k) {
        acc += __shfl(hlo, base + k, 64) * w[k * 32 + j];
        acc += __shfl(hhi, base + k, 64) * w[(32 + k) * 32 + j];
    }
    hw2[node * 32 + j] = acc;
}

// ---------------- link prediction head ----------------
// One wave per label edge: lanes 0-31 handle z[s], lanes 32-63 handle z[d].
__global__ __launch_bounds__(256) void k_linkpred(const int* __restrict__ sidx,
                                                  const int* __restrict__ didx,
                                                  const float* __restrict__ z,
                                                  const float* __restrict__ Wl,
                                                  const float* __restrict__ bl,
                                                  float* __restrict__ pred) {
    int t = blockIdx.x * blockDim.x + threadIdx.x;
    int lane = t & 63;
    int e = t >> 6;
    if (e >= NEL) return;
    float wv = Wl[lane];
    int node = (lane < 32) ? sidx[e] : didx[e];
    float v = z[node * 32 + (lane & 31)] * wv;
#pragma unroll
    for (int off = 32; off > 0; off >>= 1) v += __shfl_down(v, off, 64);
    if (lane == 0) pred[e] = v + bl[0];
}

extern "C" void kernel_launch(void* const* d_in, const int* in_sizes, int n_in,
                              void* d_out, int out_size, void* d_ws, size_t ws_size,
                              hipStream_t stream) {
    const float* x    = (const float*)d_in[0];
    const float* pos  = (const float*)d_in[1];
    const float* W1   = (const float*)d_in[2];
    const float* b1   = (const float*)d_in[3];
    const float* W2   = (const float*)d_in[4];
    const float* b2   = (const float*)d_in[5];
    const float* Wl   = (const float*)d_in[6];
    const float* bl   = (const float*)d_in[7];
    const int*   ei   = (const int*)d_in[8];   // [2, NE]
    const int*   eli  = (const int*)d_in[9];   // [2, NEL]
    const int* src  = ei;
    const int* dst  = ei + NE;
    const int* lsrc = eli;
    const int* ldst = eli + NEL;

    float* out_z    = (float*)d_out;            // [NN, 32]
    float* out_pred = (float*)d_out + NN * 32;  // [NEL]

    // workspace layout (floats): dinv[NN] | bufA[NN*64] | bufB[NN*64]
    float* dinv = (float*)d_ws;
    float* bufA = dinv + NN;          // hw1, later hw2 (first half)
    float* bufB = bufA + NN * 64;     // agg1 -> h2 (in place)

    // 1) degree + norm
    k_init_deg<<<(NN + 255) / 256, 256, 0, stream>>>(dinv);
    k_count_deg<<<(NE + 255) / 256, 256, 0, stream>>>(dst, dinv);
    k_rsqrt<<<(NN + 255) / 256, 256, 0, stream>>>(dinv);

    // 2) hw1 = [x|pos] @ W1
    k_hw1<<<NN / 4, 256, 0, stream>>>(x, pos, W1, bufA);

    // 3) layer-1 aggregation into bufB
    k_init_agg<<<(NN * 64 + 255) / 256, 256, 0, stream>>>(bufA, dinv, bufB, NN * 64, 6);
    k_scatter<64><<<8192, 256, 0, stream>>>(src, dst, dinv, bufA, bufB);
    k_bias_relu<<<(NN * 64 + 255) / 256, 256, 0, stream>>>(bufB, b1, NN * 64, 63, 1);

    // 4) hw2 = h2 @ W2 (h2 = bufB, hw2 -> bufA reuse)
    k_hw2<<<NN / 8, 256, 0, stream>>>(bufB, W2, bufA);

    // 5) layer-2 aggregation directly into d_out z region
    k_init_agg<<<(NN * 32 + 255) / 256, 256, 0, stream>>>(bufA, dinv, out_z, NN * 32, 5);
    k_scatter<32><<<8192, 256, 0, stream>>>(src, dst, dinv, bufA, out_z);
    k_bias_relu<<<(NN * 32 + 255) / 256, 256, 0, stream>>>(out_z, b2, NN * 32, 31, 0);

    // 6) link prediction
    k_linkpred<<<(NEL * 64 + 255) / 256, 256, 0, stream>>>(lsrc, ldst, out_z, Wl, bl, out_pred);
}

// Round 4
// 617.480 us; speedup vs baseline: 1.4682x; 1.4682x over previous
//
#include <hip/hip_runtime.h>

#define NN 100000     // num nodes
#define NE 1600000    // num edges
#define NEL 200000    // link-pred edges
#define NB 391        // (NN+255)/256 scan blocks

// ---------------- CSR build ----------------
__global__ void k_zero(int* __restrict__ c) {
    int i = blockIdx.x * blockDim.x + threadIdx.x;
    if (i < NN) c[i] = 0;
}

__global__ void k_hist(const int* __restrict__ dst, int* __restrict__ c) {
    int i = blockIdx.x * blockDim.x + threadIdx.x;
    if (i < NE) atomicAdd(&c[dst[i]], 1);
}

__global__ void k_dinv(const int* __restrict__ c, float* __restrict__ dinv) {
    int i = blockIdx.x * blockDim.x + threadIdx.x;
    if (i < NN) dinv[i] = rsqrtf((float)(c[i] + 1));   // +1 self-loop
}

__global__ void k_bsum(const int* __restrict__ c, int* __restrict__ bsum) {
    __shared__ int s[256];
    int t = threadIdx.x, i = blockIdx.x * 256 + t;
    s[t] = (i < NN) ? c[i] : 0;
    __syncthreads();
    for (int st = 128; st > 0; st >>= 1) {
        if (t < st) s[t] += s[t + st];
        __syncthreads();
    }
    if (t == 0) bsum[blockIdx.x] = s[0];
}

__global__ void k_bscan(const int* __restrict__ bsum, int* __restrict__ ebsum) {
    __shared__ int s[512];
    int t = threadIdx.x;
    int v = (t < NB) ? bsum[t] : 0;
    s[t] = v;
    __syncthreads();
    for (int st = 1; st < 512; st <<= 1) {
        int tmp = (t >= st) ? s[t - st] : 0;
        __syncthreads();
        s[t] += tmp;
        __syncthreads();
    }
    if (t < NB) ebsum[t] = s[t] - v;   // exclusive
}

__global__ void k_offsets(int* __restrict__ c, const int* __restrict__ ebsum) {
    __shared__ int s[256];
    int t = threadIdx.x, i = blockIdx.x * 256 + t;
    int v = (i < NN) ? c[i] : 0;
    s[t] = v;
    __syncthreads();
    for (int st = 1; st < 256; st <<= 1) {
        int tmp = (t >= st) ? s[t - st] : 0;
        __syncthreads();
        s[t] += tmp;
        __syncthreads();
    }
    if (i < NN) c[i] = ebsum[blockIdx.x] + s[t] - v;   // exclusive offsets (in place)
}

__global__ void k_fill(const int* __restrict__ src, const int* __restrict__ dst,
                       int* __restrict__ off, int* __restrict__ csr) {
    int e = blockIdx.x * blockDim.x + threadIdx.x;
    if (e < NE) {
        int d = dst[e];
        int p = atomicAdd(&off[d], 1);
        csr[p] = src[e];
    }
    // post-fill: off[d] == end of row d; row d = [off[d-1], off[d]), off[-1]=0
}

// ---------------- hw1 = [x | pos] @ W1  (80 -> 64), raw (no scaling) -------
__global__ __launch_bounds__(256) void k_hw1(const float* __restrict__ x,
                                             const float* __restrict__ pos,
                                             const float* __restrict__ W1,
                                             float* __restrict__ hw1) {
    __shared__ float w[80 * 64];
    for (int t = threadIdx.x; t < 80 * 64; t += 256) w[t] = W1[t];
    __syncthreads();
    int lane = threadIdx.x & 63;
    int wave = threadIdx.x >> 6;
    int node = blockIdx.x * 4 + wave;          // grid = NN/4 exactly
    float hx = x[node * 64 + lane];
    float hp = (lane < 16) ? pos[node * 16 + lane] : 0.0f;
    float acc = 0.0f;
#pragma unroll 8
    for (int k = 0; k < 64; ++k)
        acc += __shfl(hx, k, 64) * w[k * 64 + lane];
#pragma unroll
    for (int k = 0; k < 16; ++k)
        acc += __shfl(hp, k, 64) * w[(64 + k) * 64 + lane];
    hw1[node * 64 + lane] = acc;
}

// ---------------- fused layer-1 gather + ReLU + W2 transform ----------------
// h2[d][c] = relu(b1[c] + sum_e hw1[s]*dinv[s]*dinv[d] + hw1[d]*dinv[d]^2)
// hw2[d][j] = sum_k h2[d][k] * W2[k][j]      (raw, no dinv scaling)
// NOTE: all shuffles here execute with wave-uniform trip counts (full exec).
__global__ __launch_bounds__(256) void k_gather1_fused(const int* __restrict__ off,
                                                       const int* __restrict__ csr,
                                                       const float* __restrict__ dinv,
                                                       const float* __restrict__ hw,
                                                       const float* __restrict__ b1,
                                                       const float* __restrict__ W2,
                                                       float* __restrict__ hw2) {
    __shared__ float w[64 * 32];
    for (int t = threadIdx.x; t < 64 * 32; t += 256) w[t] = W2[t];
    __syncthreads();
    int lane = threadIdx.x & 63;
    int wave = threadIdx.x >> 6;
    int d = blockIdx.x * 4 + wave;             // grid = NN/4 exactly
    int start = (d == 0) ? 0 : off[d - 1];
    int end = off[d];
    float dd = dinv[d];
    float acc0 = 0.0f, acc1 = 0.0f;
    for (int base = start; base < end; base += 64) {
        int idx = base + lane;
        int sv = 0; float dn = 0.0f;
        if (idx < end) { sv = csr[idx]; dn = dinv[sv]; }
        int n = min(64, end - base);
        int jj = 0;
        for (; jj + 1 < n; jj += 2) {          // uniform: jj, n wave-uniform
            int   s0 = __shfl(sv, jj, 64);
            float n0 = __shfl(dn, jj, 64) * dd;
            int   s1 = __shfl(sv, jj + 1, 64);
            float n1 = __shfl(dn, jj + 1, 64) * dd;
            acc0 += hw[s0 * 64 + lane] * n0;
            acc1 += hw[s1 * 64 + lane] * n1;
        }
        if (jj < n) {                           // uniform branch, full exec
            int   s0 = __shfl(sv, jj, 64);
            float n0 = __shfl(dn, jj, 64) * dd;
            acc0 += hw[s0 * 64 + lane] * n0;
        }
    }
    float v = fmaxf(b1[lane] + (acc0 + acc1 + hw[d * 64 + lane] * dd * dd), 0.0f);
    // in-wave h2 @ W2: lane L handles out channel j=L&31, k-range [base2, base2+32)
    int j = lane & 31;
    int base2 = (lane >> 5) << 5;              // 0 for lanes 0-31, 32 for 32-63
    float acc = 0.0f;
#pragma unroll 8
    for (int k = 0; k < 32; ++k)
        acc += __shfl(v, base2 + k, 64) * w[(base2 + k) * 32 + j];
    acc += __shfl(acc, lane ^ 32, 64);         // combine k-halves
    if (lane < 32) hw2[d * 32 + j] = acc;
}

// ---------------- layer-2 gather (C=32, 2 edges/iter) ----------------------
// z[d][j] = b2[j] + sum_e hw2[s]*dinv[s]*dinv[d] + hw2[d]*dinv[d]^2
// BUGFIX (R1/R2): the old loop `for (jj=half; jj<n; jj+=2)` gave half-0 lanes
// one extra iteration when n is odd -> __shfl executed with lanes 32-63
// inactive -> ds_bpermute from inactive source lanes -> dropped edge for rows
// with odd tail count. Fix: uniform even bound nceil; the padding iteration
// shuffles from lane n (valid, active, holds sv=0/dn=0) -> contributes 0.
__global__ __launch_bounds__(256) void k_gather2(const int* __restrict__ off,
                                                 const int* __restrict__ csr,
                                                 const float* __restrict__ dinv,
                                                 const float* __restrict__ hw,
                                                 const float* __restrict__ b2,
                                                 float* __restrict__ outz) {
    int lane = threadIdx.x & 63;
    int half = lane >> 5;
    int j = lane & 31;
    int wave = threadIdx.x >> 6;
    int d = blockIdx.x * 4 + wave;             // grid = NN/4 exactly
    int start = (d == 0) ? 0 : off[d - 1];
    int end = off[d];
    float dd = dinv[d];
    float acc = 0.0f;
    for (int base = start; base < end; base += 64) {
        int idx = base + lane;
        int sv = 0; float dn = 0.0f;
        if (idx < end) { sv = csr[idx]; dn = dinv[sv]; }
        int n = min(64, end - base);
        int nceil = (n + 1) & ~1;              // uniform trip count both halves
        for (int jj = half; jj < nceil; jj += 2) {
            int   s = __shfl(sv, jj, 64);      // jj==n pad: dn=0 -> adds 0
            float nm = __shfl(dn, jj, 64) * dd;
            acc += hw[s * 32 + j] * nm;
        }
    }
    acc += __shfl(acc, lane ^ 32, 64);         // combine halves (full exec)
    if (half == 0)
        outz[d * 32 + j] = b2[j] + (acc + hw[d * 32 + j] * dd * dd);
}

// ---------------- link prediction head ----------------
__global__ __launch_bounds__(256) void k_linkpred(const int* __restrict__ sidx,
                                                  const int* __restrict__ didx,
                                                  const float* __restrict__ z,
                                                  const float* __restrict__ Wl,
                                                  const float* __restrict__ bl,
                                                  float* __restrict__ pred) {
    int t = blockIdx.x * blockDim.x + threadIdx.x;
    int lane = t & 63;
    int e = t >> 6;
    if (e >= NEL) return;                      // wave-uniform (e = t>>6)
    float wv = Wl[lane];
    int node = (lane < 32) ? sidx[e] : didx[e];
    float v = z[node * 32 + (lane & 31)] * wv;
#pragma unroll
    for (int off = 32; off > 0; off >>= 1) v += __shfl_down(v, off, 64);
    if (lane == 0) pred[e] = v + bl[0];
}

extern "C" void kernel_launch(void* const* d_in, const int* in_sizes, int n_in,
                              void* d_out, int out_size, void* d_ws, size_t ws_size,
                              hipStream_t stream) {
    const float* x    = (const float*)d_in[0];
    const float* pos  = (const float*)d_in[1];
    const float* W1   = (const float*)d_in[2];
    const float* b1   = (const float*)d_in[3];
    const float* W2   = (const float*)d_in[4];
    const float* b2   = (const float*)d_in[5];
    const float* Wl   = (const float*)d_in[6];
    const float* bl   = (const float*)d_in[7];
    const int*   ei   = (const int*)d_in[8];   // [2, NE]
    const int*   eli  = (const int*)d_in[9];   // [2, NEL]
    const int* src  = ei;
    const int* dst  = ei + NE;
    const int* lsrc = eli;
    const int* ldst = eli + NEL;

    float* out_z    = (float*)d_out;            // [NN, 32]
    float* out_pred = (float*)d_out + NN * 32;  // [NEL]

    // workspace (4B elems): dinv[NN] | off[NN] | bsum[NB] | ebsum[NB] |
    //                       csr[NE] | hw1[NN*64] | hw2[NN*32]   = 45.6 MB total
    float* dinv  = (float*)d_ws;
    int*   off   = (int*)(dinv + NN);
    int*   bsum  = off + NN;
    int*   ebsum = bsum + NB;
    int*   csr   = ebsum + NB;
    float* hw1   = (float*)(csr + NE);
    float* hw2   = hw1 + NN * 64;

    // 1) CSR build + dinv
    k_zero<<<(NN + 255) / 256, 256, 0, stream>>>(off);
    k_hist<<<(NE + 255) / 256, 256, 0, stream>>>(dst, off);
    k_dinv<<<(NN + 255) / 256, 256, 0, stream>>>(off, dinv);
    k_bsum<<<NB, 256, 0, stream>>>(off, bsum);
    k_bscan<<<1, 512, 0, stream>>>(bsum, ebsum);
    k_offsets<<<NB, 256, 0, stream>>>(off, ebsum);
    k_fill<<<(NE + 255) / 256, 256, 0, stream>>>(src, dst, off, csr);

    // 2) hw1 = [x|pos] @ W1 (raw)
    k_hw1<<<NN / 4, 256, 0, stream>>>(x, pos, W1, hw1);

    // 3) fused: layer-1 gather + bias + relu + (@W2) -> hw2 (raw)
    k_gather1_fused<<<NN / 4, 256, 0, stream>>>(off, csr, dinv, hw1, b1, W2, hw2);

    // 4) layer-2 gather + bias -> z
    k_gather2<<<NN / 4, 256, 0, stream>>>(off, csr, dinv, hw2, b2, out_z);

    // 5) link prediction
    k_linkpred<<<(NEL * 64 + 255) / 256, 256, 0, stream>>>(lsrc, ldst, out_z, Wl, bl, out_pred);
}

// Round 5
// 530.515 us; speedup vs baseline: 1.7089x; 1.1639x over previous
//
#include <hip/hip_runtime.h>

#define NN 100000     // num nodes
#define NE 1600000    // num edges
#define NEL 200000    // link-pred edges
#define NB 391        // (NN+255)/256 scan blocks
#define TM 64         // nodes per block in k_hw1

// ---------------- CSR build ----------------
__global__ void k_zero(int* __restrict__ c) {
    int i = blockIdx.x * blockDim.x + threadIdx.x;
    if (i < NN) c[i] = 0;
}

__global__ void k_hist(const int* __restrict__ dst, int* __restrict__ c) {
    int i = blockIdx.x * blockDim.x + threadIdx.x;
    if (i < NE) atomicAdd(&c[dst[i]], 1);
}

__global__ void k_dinv(const int* __restrict__ c, float* __restrict__ dinv) {
    int i = blockIdx.x * blockDim.x + threadIdx.x;
    if (i < NN) dinv[i] = rsqrtf((float)(c[i] + 1));   // +1 self-loop
}

__global__ void k_bsum(const int* __restrict__ c, int* __restrict__ bsum) {
    __shared__ int s[256];
    int t = threadIdx.x, i = blockIdx.x * 256 + t;
    s[t] = (i < NN) ? c[i] : 0;
    __syncthreads();
    for (int st = 128; st > 0; st >>= 1) {
        if (t < st) s[t] += s[t + st];
        __syncthreads();
    }
    if (t == 0) bsum[blockIdx.x] = s[0];
}

__global__ void k_bscan(const int* __restrict__ bsum, int* __restrict__ ebsum) {
    __shared__ int s[512];
    int t = threadIdx.x;
    int v = (t < NB) ? bsum[t] : 0;
    s[t] = v;
    __syncthreads();
    for (int st = 1; st < 512; st <<= 1) {
        int tmp = (t >= st) ? s[t - st] : 0;
        __syncthreads();
        s[t] += tmp;
        __syncthreads();
    }
    if (t < NB) ebsum[t] = s[t] - v;   // exclusive
}

__global__ void k_offsets(int* __restrict__ c, const int* __restrict__ ebsum) {
    __shared__ int s[256];
    int t = threadIdx.x, i = blockIdx.x * 256 + t;
    int v = (i < NN) ? c[i] : 0;
    s[t] = v;
    __syncthreads();
    for (int st = 1; st < 256; st <<= 1) {
        int tmp = (t >= st) ? s[t - st] : 0;
        __syncthreads();
        s[t] += tmp;
        __syncthreads();
    }
    if (i < NN) c[i] = ebsum[blockIdx.x] + s[t] - v;   // exclusive offsets (in place)
}

__global__ void k_fill(const int* __restrict__ src, const int* __restrict__ dst,
                       int* __restrict__ off, int* __restrict__ csr) {
    int e = blockIdx.x * blockDim.x + threadIdx.x;
    if (e < NE) {
        int d = dst[e];
        int p = atomicAdd(&off[d], 1);
        csr[p] = src[e];
    }
    // post-fill: off[d] == end of row d; row d = [off[d-1], off[d]), off[-1]=0
}

// ---------------- hw1 = [x | pos] @ W1  (80 -> 64), tiled GEMM -------------
// Block: 256 threads, TM=64 nodes. LDS: h[64 nodes][80 feat] + W1[80][64].
// Thread (tid) owns 4 nodes x 4 channels in registers.
// Per k-step: 1 ds_read_b128 (W row chunk, 2-way = free) + 4 broadcast
// ds_read_b32 (h) feeding 16 FMAs -> VALU-bound instead of LDS-bound.
__global__ __launch_bounds__(256) void k_hw1(const float* __restrict__ x,
                                             const float* __restrict__ pos,
                                             const float* __restrict__ W1,
                                             float* __restrict__ hw1) {
    __shared__ float sh[TM * 80];   // [node][feat 0..79]
    __shared__ float sw[80 * 64];   // [k][j]
    int tid = threadIdx.x;
    for (int t = tid; t < 80 * 64; t += 256) sw[t] = W1[t];
    int nb = blockIdx.x * TM;
    for (int i = tid; i < TM * 64; i += 256) {       // x part (coalesced)
        int node = i >> 6, ch = i & 63;
        int g = nb + node;
        sh[node * 80 + ch] = (g < NN) ? x[g * 64 + ch] : 0.0f;
    }
    for (int i = tid; i < TM * 16; i += 256) {       // pos part (coalesced)
        int node = i >> 4, ch = i & 15;
        int g = nb + node;
        sh[node * 80 + 64 + ch] = (g < NN) ? pos[g * 16 + ch] : 0.0f;
    }
    __syncthreads();
    int j  = (tid & 15) * 4;        // output channel base
    int nl = (tid >> 4) * 4;        // local node base
    float a00=0,a01=0,a02=0,a03=0, a10=0,a11=0,a12=0,a13=0;
    float a20=0,a21=0,a22=0,a23=0, a30=0,a31=0,a32=0,a33=0;
#pragma unroll 4
    for (int k = 0; k < 80; ++k) {
        float4 wv = *(const float4*)&sw[k * 64 + j];
        float h0 = sh[(nl + 0) * 80 + k];
        float h1 = sh[(nl + 1) * 80 + k];
        float h2 = sh[(nl + 2) * 80 + k];
        float h3 = sh[(nl + 3) * 80 + k];
        a00 += h0 * wv.x; a01 += h0 * wv.y; a02 += h0 * wv.z; a03 += h0 * wv.w;
        a10 += h1 * wv.x; a11 += h1 * wv.y; a12 += h1 * wv.z; a13 += h1 * wv.w;
        a20 += h2 * wv.x; a21 += h2 * wv.y; a22 += h2 * wv.z; a23 += h2 * wv.w;
        a30 += h3 * wv.x; a31 += h3 * wv.y; a32 += h3 * wv.z; a33 += h3 * wv.w;
    }
    int g0 = nb + nl;
    if (g0 + 0 < NN) *(float4*)&hw1[(g0 + 0) * 64 + j] = make_float4(a00, a01, a02, a03);
    if (g0 + 1 < NN) *(float4*)&hw1[(g0 + 1) * 64 + j] = make_float4(a10, a11, a12, a13);
    if (g0 + 2 < NN) *(float4*)&hw1[(g0 + 2) * 64 + j] = make_float4(a20, a21, a22, a23);
    if (g0 + 3 < NN) *(float4*)&hw1[(g0 + 3) * 64 + j] = make_float4(a30, a31, a32, a33);
}

// ---------------- fused layer-1 gather + ReLU + W2 transform ----------------
// h2[d][c] = relu(b1[c] + sum_e hw1[s]*dinv[s]*dinv[d] + hw1[d]*dinv[d]^2)
// hw2[d][j] = sum_k h2[d][k] * W2[k][j]      (raw, no dinv scaling)
// NOTE: all shuffles here execute with wave-uniform trip counts (full exec).
__global__ __launch_bounds__(256) void k_gather1_fused(const int* __restrict__ off,
                                                       const int* __restrict__ csr,
                                                       const float* __restrict__ dinv,
                                                       const float* __restrict__ hw,
                                                       const float* __restrict__ b1,
                                                       const float* __restrict__ W2,
                                                       float* __restrict__ hw2) {
    __shared__ float w[64 * 32];
    for (int t = threadIdx.x; t < 64 * 32; t += 256) w[t] = W2[t];
    __syncthreads();
    int lane = threadIdx.x & 63;
    int wave = threadIdx.x >> 6;
    int d = blockIdx.x * 4 + wave;             // grid = NN/4 exactly
    int start = (d == 0) ? 0 : off[d - 1];
    int end = off[d];
    float dd = dinv[d];
    float acc0 = 0.0f, acc1 = 0.0f;
    for (int base = start; base < end; base += 64) {
        int idx = base + lane;
        int sv = 0; float dn = 0.0f;
        if (idx < end) { sv = csr[idx]; dn = dinv[sv]; }
        int n = min(64, end - base);
        int jj = 0;
        for (; jj + 1 < n; jj += 2) {          // uniform: jj, n wave-uniform
            int   s0 = __shfl(sv, jj, 64);
            float n0 = __shfl(dn, jj, 64) * dd;
            int   s1 = __shfl(sv, jj + 1, 64);
            float n1 = __shfl(dn, jj + 1, 64) * dd;
            acc0 += hw[s0 * 64 + lane] * n0;
            acc1 += hw[s1 * 64 + lane] * n1;
        }
        if (jj < n) {                           // uniform branch, full exec
            int   s0 = __shfl(sv, jj, 64);
            float n0 = __shfl(dn, jj, 64) * dd;
            acc0 += hw[s0 * 64 + lane] * n0;
        }
    }
    float v = fmaxf(b1[lane] + (acc0 + acc1 + hw[d * 64 + lane] * dd * dd), 0.0f);
    // in-wave h2 @ W2: lane L handles out channel j=L&31, k-range [base2, base2+32)
    int j = lane & 31;
    int base2 = (lane >> 5) << 5;              // 0 for lanes 0-31, 32 for 32-63
    float acc = 0.0f;
#pragma unroll 8
    for (int k = 0; k < 32; ++k)
        acc += __shfl(v, base2 + k, 64) * w[(base2 + k) * 32 + j];
    acc += __shfl(acc, lane ^ 32, 64);         // combine k-halves
    if (lane < 32) hw2[d * 32 + j] = acc;
}

// ---------------- layer-2 gather (C=32, 2 edges/iter) ----------------------
// z[d][j] = b2[j] + sum_e hw2[s]*dinv[s]*dinv[d] + hw2[d]*dinv[d]^2
// Uniform even bound nceil keeps both 32-lane halves in lockstep (full exec);
// the padding iteration shuffles from lane n (valid, holds sv=0/dn=0) -> +0.
__global__ __launch_bounds__(256) void k_gather2(const int* __restrict__ off,
                                                 const int* __restrict__ csr,
                                                 const float* __restrict__ dinv,
                                                 const float* __restrict__ hw,
                                                 const float* __restrict__ b2,
                                                 float* __restrict__ outz) {
    int lane = threadIdx.x & 63;
    int half = lane >> 5;
    int j = lane & 31;
    int wave = threadIdx.x >> 6;
    int d = blockIdx.x * 4 + wave;             // grid = NN/4 exactly
    int start = (d == 0) ? 0 : off[d - 1];
    int end = off[d];
    float dd = dinv[d];
    float acc = 0.0f;
    for (int base = start; base < end; base += 64) {
        int idx = base + lane;
        int sv = 0; float dn = 0.0f;
        if (idx < end) { sv = csr[idx]; dn = dinv[sv]; }
        int n = min(64, end - base);
        int nceil = (n + 1) & ~1;              // uniform trip count both halves
        for (int jj = half; jj < nceil; jj += 2) {
            int   s = __shfl(sv, jj, 64);      // jj==n pad: dn=0 -> adds 0
            float nm = __shfl(dn, jj, 64) * dd;
            acc += hw[s * 32 + j] * nm;
        }
    }
    acc += __shfl(acc, lane ^ 32, 64);         // combine halves (full exec)
    if (half == 0)
        outz[d * 32 + j] = b2[j] + (acc + hw[d * 32 + j] * dd * dd);
}

// ---------------- link prediction head ----------------
__global__ __launch_bounds__(256) void k_linkpred(const int* __restrict__ sidx,
                                                  const int* __restrict__ didx,
                                                  const float* __restrict__ z,
                                                  const float* __restrict__ Wl,
                                                  const float* __restrict__ bl,
                                                  float* __restrict__ pred) {
    int t = blockIdx.x * blockDim.x + threadIdx.x;
    int lane = t & 63;
    int e = t >> 6;
    if (e >= NEL) return;                      // wave-uniform (e = t>>6)
    float wv = Wl[lane];
    int node = (lane < 32) ? sidx[e] : didx[e];
    float v = z[node * 32 + (lane & 31)] * wv;
#pragma unroll
    for (int off = 32; off > 0; off >>= 1) v += __shfl_down(v, off, 64);
    if (lane == 0) pred[e] = v + bl[0];
}

extern "C" void kernel_launch(void* const* d_in, const int* in_sizes, int n_in,
                              void* d_out, int out_size, void* d_ws, size_t ws_size,
                              hipStream_t stream) {
    const float* x    = (const float*)d_in[0];
    const float* pos  = (const float*)d_in[1];
    const float* W1   = (const float*)d_in[2];
    const float* b1   = (const float*)d_in[3];
    const float* W2   = (const float*)d_in[4];
    const float* b2   = (const float*)d_in[5];
    const float* Wl   = (const float*)d_in[6];
    const float* bl   = (const float*)d_in[7];
    const int*   ei   = (const int*)d_in[8];   // [2, NE]
    const int*   eli  = (const int*)d_in[9];   // [2, NEL]
    const int* src  = ei;
    const int* dst  = ei + NE;
    const int* lsrc = eli;
    const int* ldst = eli + NEL;

    float* out_z    = (float*)d_out;            // [NN, 32]
    float* out_pred = (float*)d_out + NN * 32;  // [NEL]

    // workspace (4B elems): dinv[NN] | off[NN] | bsum[NB] | ebsum[NB] |
    //                       csr[NE] | hw1[NN*64] | hw2[NN*32]   = 45.6 MB total
    float* dinv  = (float*)d_ws;
    int*   off   = (int*)(dinv + NN);
    int*   bsum  = off + NN;
    int*   ebsum = bsum + NB;
    int*   csr   = ebsum + NB;
    float* hw1   = (float*)(csr + NE);
    float* hw2   = hw1 + NN * 64;

    // 1) CSR build + dinv
    k_zero<<<(NN + 255) / 256, 256, 0, stream>>>(off);
    k_hist<<<(NE + 255) / 256, 256, 0, stream>>>(dst, off);
    k_dinv<<<(NN + 255) / 256, 256, 0, stream>>>(off, dinv);
    k_bsum<<<NB, 256, 0, stream>>>(off, bsum);
    k_bscan<<<1, 512, 0, stream>>>(bsum, ebsum);
    k_offsets<<<NB, 256, 0, stream>>>(off, ebsum);
    k_fill<<<(NE + 255) / 256, 256, 0, stream>>>(src, dst, off, csr);

    // 2) hw1 = [x|pos] @ W1 (raw), tiled GEMM
    k_hw1<<<(NN + TM - 1) / TM, 256, 0, stream>>>(x, pos, W1, hw1);

    // 3) fused: layer-1 gather + bias + relu + (@W2) -> hw2 (raw)
    k_gather1_fused<<<NN / 4, 256, 0, stream>>>(off, csr, dinv, hw1, b1, W2, hw2);

    // 4) layer-2 gather + bias -> z
    k_gather2<<<NN / 4, 256, 0, stream>>>(off, csr, dinv, hw2, b2, out_z);

    // 5) link prediction
    k_linkpred<<<(NEL * 64 + 255) / 256, 256, 0, stream>>>(lsrc, ldst, out_z, Wl, bl, out_pred);
}

// Round 6
// 483.548 us; speedup vs baseline: 1.8749x; 1.0971x over previous
//
#include <hip/hip_runtime.h>

#define NN 100000     // num nodes
#define NE 1600000    // num edges
#define NEL 200000    // link-pred edges
#define NB 391        // (NN+255)/256 scan blocks
#define TM 64         // nodes per block in k_hw1
#define NGRP 8        // XCD partitions for CSR build
#define RNG (NN / NGRP)   // 12500 dst-nodes per partition

// ---------------- CSR build ----------------
__global__ void k_zero(int* __restrict__ c) {
    int i = blockIdx.x * blockDim.x + threadIdx.x;
    if (i < NN) c[i] = 0;
}

// Partitioned histogram: group g = blockIdx&7 (XCD swizzle heuristic) counts
// only dst in [g*RNG,(g+1)*RNG) -> atomics stay in one XCD's L2 slice.
__global__ __launch_bounds__(256) void k_hist(const int* __restrict__ dst,
                                              int* __restrict__ c) {
    int g  = blockIdx.x & 7;
    int kg = blockIdx.x >> 3;
    int lo = g * RNG, hi = lo + RNG;
    int stride = (gridDim.x >> 3) * 256;
    for (int e = kg * 256 + threadIdx.x; e < NE; e += stride) {
        int d = dst[e];
        if (d >= lo && d < hi) atomicAdd(&c[d], 1);
    }
}

__global__ void k_dinv(const int* __restrict__ c, float* __restrict__ dinv) {
    int i = blockIdx.x * blockDim.x + threadIdx.x;
    if (i < NN) dinv[i] = rsqrtf((float)(c[i] + 1));   // +1 self-loop
}

__global__ void k_bsum(const int* __restrict__ c, int* __restrict__ bsum) {
    __shared__ int s[256];
    int t = threadIdx.x, i = blockIdx.x * 256 + t;
    s[t] = (i < NN) ? c[i] : 0;
    __syncthreads();
    for (int st = 128; st > 0; st >>= 1) {
        if (t < st) s[t] += s[t + st];
        __syncthreads();
    }
    if (t == 0) bsum[blockIdx.x] = s[0];
}

__global__ void k_bscan(const int* __restrict__ bsum, int* __restrict__ ebsum) {
    __shared__ int s[512];
    int t = threadIdx.x;
    int v = (t < NB) ? bsum[t] : 0;
    s[t] = v;
    __syncthreads();
    for (int st = 1; st < 512; st <<= 1) {
        int tmp = (t >= st) ? s[t - st] : 0;
        __syncthreads();
        s[t] += tmp;
        __syncthreads();
    }
    if (t < NB) ebsum[t] = s[t] - v;   // exclusive
}

__global__ void k_offsets(int* __restrict__ c, const int* __restrict__ ebsum) {
    __shared__ int s[256];
    int t = threadIdx.x, i = blockIdx.x * 256 + t;
    int v = (i < NN) ? c[i] : 0;
    s[t] = v;
    __syncthreads();
    for (int st = 1; st < 256; st <<= 1) {
        int tmp = (t >= st) ? s[t - st] : 0;
        __syncthreads();
        s[t] += tmp;
        __syncthreads();
    }
    if (i < NN) c[i] = ebsum[blockIdx.x] + s[t] - v;   // exclusive offsets (in place)
}

// Partitioned fill: group g handles only its dst range -> cursor atomics and
// csr[p] data writes land in an 850 KB slice resident in one XCD's L2, so
// each 64B line accumulates all 16 entries before one final eviction
// (R4 measured 105 MB WRITE for the unpartitioned version vs 6.4 MB ideal).
__global__ __launch_bounds__(256) void k_fill(const int* __restrict__ src,
                                              const int* __restrict__ dst,
                                              int* __restrict__ off,
                                              int* __restrict__ csr) {
    int g  = blockIdx.x & 7;
    int kg = blockIdx.x >> 3;
    int lo = g * RNG, hi = lo + RNG;
    int stride = (gridDim.x >> 3) * 256;
    for (int e = kg * 256 + threadIdx.x; e < NE; e += stride) {
        int d = dst[e];
        if (d >= lo && d < hi) {
            int p = atomicAdd(&off[d], 1);
            csr[p] = src[e];
        }
    }
    // post-fill: off[d] == end of row d; row d = [off[d-1], off[d]), off[-1]=0
}

// ---------------- hw1 = [x | pos] @ W1  (80 -> 64), tiled GEMM -------------
__global__ __launch_bounds__(256) void k_hw1(const float* __restrict__ x,
                                             const float* __restrict__ pos,
                                             const float* __restrict__ W1,
                                             float* __restrict__ hw1) {
    __shared__ float sh[TM * 80];   // [node][feat 0..79]
    __shared__ float sw[80 * 64];   // [k][j]
    int tid = threadIdx.x;
    for (int t = tid; t < 80 * 64; t += 256) sw[t] = W1[t];
    int nb = blockIdx.x * TM;
    for (int i = tid; i < TM * 64; i += 256) {       // x part (coalesced)
        int node = i >> 6, ch = i & 63;
        int g = nb + node;
        sh[node * 80 + ch] = (g < NN) ? x[g * 64 + ch] : 0.0f;
    }
    for (int i = tid; i < TM * 16; i += 256) {       // pos part (coalesced)
        int node = i >> 4, ch = i & 15;
        int g = nb + node;
        sh[node * 80 + 64 + ch] = (g < NN) ? pos[g * 16 + ch] : 0.0f;
    }
    __syncthreads();
    int j  = (tid & 15) * 4;        // output channel base
    int nl = (tid >> 4) * 4;        // local node base
    float a00=0,a01=0,a02=0,a03=0, a10=0,a11=0,a12=0,a13=0;
    float a20=0,a21=0,a22=0,a23=0, a30=0,a31=0,a32=0,a33=0;
#pragma unroll 4
    for (int k = 0; k < 80; ++k) {
        float4 wv = *(const float4*)&sw[k * 64 + j];
        float h0 = sh[(nl + 0) * 80 + k];
        float h1 = sh[(nl + 1) * 80 + k];
        float h2 = sh[(nl + 2) * 80 + k];
        float h3 = sh[(nl + 3) * 80 + k];
        a00 += h0 * wv.x; a01 += h0 * wv.y; a02 += h0 * wv.z; a03 += h0 * wv.w;
        a10 += h1 * wv.x; a11 += h1 * wv.y; a12 += h1 * wv.z; a13 += h1 * wv.w;
        a20 += h2 * wv.x; a21 += h2 * wv.y; a22 += h2 * wv.z; a23 += h2 * wv.w;
        a30 += h3 * wv.x; a31 += h3 * wv.y; a32 += h3 * wv.z; a33 += h3 * wv.w;
    }
    int g0 = nb + nl;
    if (g0 + 0 < NN) *(float4*)&hw1[(g0 + 0) * 64 + j] = make_float4(a00, a01, a02, a03);
    if (g0 + 1 < NN) *(float4*)&hw1[(g0 + 1) * 64 + j] = make_float4(a10, a11, a12, a13);
    if (g0 + 2 < NN) *(float4*)&hw1[(g0 + 2) * 64 + j] = make_float4(a20, a21, a22, a23);
    if (g0 + 3 < NN) *(float4*)&hw1[(g0 + 3) * 64 + j] = make_float4(a30, a31, a32, a33);
}

// ---------------- fused layer-1 gather + ReLU + W2 transform ----------------
// h2[d][c] = relu(b1[c] + sum_e hw1[s]*dinv[s]*dinv[d] + hw1[d]*dinv[d]^2)
// hw2[d][j] = sum_k h2[d][k] * W2[k][j]      (raw, no dinv scaling)
// NOTE: all shuffles execute with wave-uniform trip counts (full exec).
__global__ __launch_bounds__(256) void k_gather1_fused(const int* __restrict__ off,
                                                       const int* __restrict__ csr,
                                                       const float* __restrict__ dinv,
                                                       const float* __restrict__ hw,
                                                       const float* __restrict__ b1,
                                                       const float* __restrict__ W2,
                                                       float* __restrict__ hw2) {
    __shared__ float w[64 * 32];
    for (int t = threadIdx.x; t < 64 * 32; t += 256) w[t] = W2[t];
    __syncthreads();
    int lane = threadIdx.x & 63;
    int wave = threadIdx.x >> 6;
    int d = blockIdx.x * 4 + wave;             // grid = NN/4 exactly
    int start = (d == 0) ? 0 : off[d - 1];
    int end = off[d];
    float dd = dinv[d];
    float acc0 = 0.0f, acc1 = 0.0f;
    for (int base = start; base < end; base += 64) {
        int idx = base + lane;
        int sv = 0; float dn = 0.0f;
        if (idx < end) { sv = csr[idx]; dn = dinv[sv]; }
        int n = min(64, end - base);
        int jj = 0;
        for (; jj + 1 < n; jj += 2) {          // uniform: jj, n wave-uniform
            int   s0 = __shfl(sv, jj, 64);
            float n0 = __shfl(dn, jj, 64) * dd;
            int   s1 = __shfl(sv, jj + 1, 64);
            float n1 = __shfl(dn, jj + 1, 64) * dd;
            acc0 += hw[s0 * 64 + lane] * n0;
            acc1 += hw[s1 * 64 + lane] * n1;
        }
        if (jj < n) {                           // uniform branch, full exec
            int   s0 = __shfl(sv, jj, 64);
            float n0 = __shfl(dn, jj, 64) * dd;
            acc0 += hw[s0 * 64 + lane] * n0;
        }
    }
    float v = fmaxf(b1[lane] + (acc0 + acc1 + hw[d * 64 + lane] * dd * dd), 0.0f);
    // in-wave h2 @ W2: lane L handles out channel j=L&31, k-range [base2, base2+32)
    int j = lane & 31;
    int base2 = (lane >> 5) << 5;              // 0 for lanes 0-31, 32 for 32-63
    float acc = 0.0f;
#pragma unroll 8
    for (int k = 0; k < 32; ++k)
        acc += __shfl(v, base2 + k, 64) * w[(base2 + k) * 32 + j];
    acc += __shfl(acc, lane ^ 32, 64);         // combine k-halves
    if (lane < 32) hw2[d * 32 + j] = acc;
}

// ---------------- layer-2 gather (C=32, 2 edges/iter) ----------------------
// z[d][j] = b2[j] + sum_e hw2[s]*dinv[s]*dinv[d] + hw2[d]*dinv[d]^2
// Uniform even bound nceil keeps both 32-lane halves in lockstep (full exec);
// the padding iteration shuffles from lane n (valid, holds sv=0/dn=0) -> +0.
__global__ __launch_bounds__(256) void k_gather2(const int* __restrict__ off,
                                                 const int* __restrict__ csr,
                                                 const float* __restrict__ dinv,
                                                 const float* __restrict__ hw,
                                                 const float* __restrict__ b2,
                                                 float* __restrict__ outz) {
    int lane = threadIdx.x & 63;
    int half = lane >> 5;
    int j = lane & 31;
    int wave = threadIdx.x >> 6;
    int d = blockIdx.x * 4 + wave;             // grid = NN/4 exactly
    int start = (d == 0) ? 0 : off[d - 1];
    int end = off[d];
    float dd = dinv[d];
    float acc = 0.0f;
    for (int base = start; base < end; base += 64) {
        int idx = base + lane;
        int sv = 0; float dn = 0.0f;
        if (idx < end) { sv = csr[idx]; dn = dinv[sv]; }
        int n = min(64, end - base);
        int nceil = (n + 1) & ~1;              // uniform trip count both halves
        for (int jj = half; jj < nceil; jj += 2) {
            int   s = __shfl(sv, jj, 64);      // jj==n pad: dn=0 -> adds 0
            float nm = __shfl(dn, jj, 64) * dd;
            acc += hw[s * 32 + j] * nm;
        }
    }
    acc += __shfl(acc, lane ^ 32, 64);         // combine halves (full exec)
    if (half == 0)
        outz[d * 32 + j] = b2[j] + (acc + hw[d * 32 + j] * dd * dd);
}

// ---------------- link prediction head ----------------
__global__ __launch_bounds__(256) void k_linkpred(const int* __restrict__ sidx,
                                                  const int* __restrict__ didx,
                                                  const float* __restrict__ z,
                                                  const float* __restrict__ Wl,
                                                  const float* __restrict__ bl,
                                                  float* __restrict__ pred) {
    int t = blockIdx.x * blockDim.x + threadIdx.x;
    int lane = t & 63;
    int e = t >> 6;
    if (e >= NEL) return;                      // wave-uniform (e = t>>6)
    float wv = Wl[lane];
    int node = (lane < 32) ? sidx[e] : didx[e];
    float v = z[node * 32 + (lane & 31)] * wv;
#pragma unroll
    for (int off = 32; off > 0; off >>= 1) v += __shfl_down(v, off, 64);
    if (lane == 0) pred[e] = v + bl[0];
}

extern "C" void kernel_launch(void* const* d_in, const int* in_sizes, int n_in,
                              void* d_out, int out_size, void* d_ws, size_t ws_size,
                              hipStream_t stream) {
    const float* x    = (const float*)d_in[0];
    const float* pos  = (const float*)d_in[1];
    const float* W1   = (const float*)d_in[2];
    const float* b1   = (const float*)d_in[3];
    const float* W2   = (const float*)d_in[4];
    const float* b2   = (const float*)d_in[5];
    const float* Wl   = (const float*)d_in[6];
    const float* bl   = (const float*)d_in[7];
    const int*   ei   = (const int*)d_in[8];   // [2, NE]
    const int*   eli  = (const int*)d_in[9];   // [2, NEL]
    const int* src  = ei;
    const int* dst  = ei + NE;
    const int* lsrc = eli;
    const int* ldst = eli + NEL;

    float* out_z    = (float*)d_out;            // [NN, 32]
    float* out_pred = (float*)d_out + NN * 32;  // [NEL]

    // workspace (4B elems): dinv[NN] | off[NN] | bsum[NB] | ebsum[NB] |
    //                       csr[NE] | hw1[NN*64] | hw2[NN*32]   = 45.6 MB total
    float* dinv  = (float*)d_ws;
    int*   off   = (int*)(dinv + NN);
    int*   bsum  = off + NN;
    int*   ebsum = bsum + NB;
    int*   csr   = ebsum + NB;
    float* hw1   = (float*)(csr + NE);
    float* hw2   = hw1 + NN * 64;

    // 1) CSR build + dinv (hist/fill XCD-partitioned: grid = 8 groups x 256)
    k_zero<<<(NN + 255) / 256, 256, 0, stream>>>(off);
    k_hist<<<2048, 256, 0, stream>>>(dst, off);
    k_dinv<<<(NN + 255) / 256, 256, 0, stream>>>(off, dinv);
    k_bsum<<<NB, 256, 0, stream>>>(off, bsum);
    k_bscan<<<1, 512, 0, stream>>>(bsum, ebsum);
    k_offsets<<<NB, 256, 0, stream>>>(off, ebsum);
    k_fill<<<2048, 256, 0, stream>>>(src, dst, off, csr);

    // 2) hw1 = [x|pos] @ W1 (raw), tiled GEMM
    k_hw1<<<(NN + TM - 1) / TM, 256, 0, stream>>>(x, pos, W1, hw1);

    // 3) fused: layer-1 gather + bias + relu + (@W2) -> hw2 (raw)
    k_gather1_fused<<<NN / 4, 256, 0, stream>>>(off, csr, dinv, hw1, b1, W2, hw2);

    // 4) layer-2 gather + bias -> z
    k_gather2<<<NN / 4, 256, 0, stream>>>(off, csr, dinv, hw2, b2, out_z);

    // 5) link prediction
    k_linkpred<<<(NEL * 64 + 255) / 256, 256, 0, stream>>>(lsrc, ldst, out_z, Wl, bl, out_pred);
}

// Round 7
// 466.489 us; speedup vs baseline: 1.9435x; 1.0366x over previous
//
#include <hip/hip_runtime.h>
#include <hip/hip_fp16.h>

#define NN 100000     // num nodes
#define NE 1600000    // num edges
#define NEL 200000    // link-pred edges
#define NB 391        // (NN+255)/256 scan blocks
#define TM 64         // nodes per block in k_hw1
#define NGRP 8        // XCD partitions for CSR build
#define RNG (NN / NGRP)   // 12500 dst-nodes per partition

// ---------------- CSR build ----------------
__global__ void k_zero(int* __restrict__ c) {
    int i = blockIdx.x * blockDim.x + threadIdx.x;
    if (i < NN) c[i] = 0;
}

// Partitioned histogram: group g = blockIdx&7 (XCD swizzle heuristic) counts
// only dst in [g*RNG,(g+1)*RNG) -> atomics stay in one XCD's L2 slice.
__global__ __launch_bounds__(256) void k_hist(const int* __restrict__ dst,
                                              int* __restrict__ c) {
    int g  = blockIdx.x & 7;
    int kg = blockIdx.x >> 3;
    int lo = g * RNG, hi = lo + RNG;
    int stride = (gridDim.x >> 3) * 256;
    for (int e = kg * 256 + threadIdx.x; e < NE; e += stride) {
        int d = dst[e];
        if (d >= lo && d < hi) atomicAdd(&c[d], 1);
    }
}

__global__ void k_dinv(const int* __restrict__ c, float* __restrict__ dinv) {
    int i = blockIdx.x * blockDim.x + threadIdx.x;
    if (i < NN) dinv[i] = rsqrtf((float)(c[i] + 1));   // +1 self-loop
}

__global__ void k_bsum(const int* __restrict__ c, int* __restrict__ bsum) {
    __shared__ int s[256];
    int t = threadIdx.x, i = blockIdx.x * 256 + t;
    s[t] = (i < NN) ? c[i] : 0;
    __syncthreads();
    for (int st = 128; st > 0; st >>= 1) {
        if (t < st) s[t] += s[t + st];
        __syncthreads();
    }
    if (t == 0) bsum[blockIdx.x] = s[0];
}

__global__ void k_bscan(const int* __restrict__ bsum, int* __restrict__ ebsum) {
    __shared__ int s[512];
    int t = threadIdx.x;
    int v = (t < NB) ? bsum[t] : 0;
    s[t] = v;
    __syncthreads();
    for (int st = 1; st < 512; st <<= 1) {
        int tmp = (t >= st) ? s[t - st] : 0;
        __syncthreads();
        s[t] += tmp;
        __syncthreads();
    }
    if (t < NB) ebsum[t] = s[t] - v;   // exclusive
}

__global__ void k_offsets(int* __restrict__ c, const int* __restrict__ ebsum) {
    __shared__ int s[256];
    int t = threadIdx.x, i = blockIdx.x * 256 + t;
    int v = (i < NN) ? c[i] : 0;
    s[t] = v;
    __syncthreads();
    for (int st = 1; st < 256; st <<= 1) {
        int tmp = (t >= st) ? s[t - st] : 0;
        __syncthreads();
        s[t] += tmp;
        __syncthreads();
    }
    if (i < NN) c[i] = ebsum[blockIdx.x] + s[t] - v;   // exclusive offsets (in place)
}

// Partitioned fill (see R5: unpartitioned version wrote 105 MB for 6.4 MB csr).
__global__ __launch_bounds__(256) void k_fill(const int* __restrict__ src,
                                              const int* __restrict__ dst,
                                              int* __restrict__ off,
                                              int* __restrict__ csr) {
    int g  = blockIdx.x & 7;
    int kg = blockIdx.x >> 3;
    int lo = g * RNG, hi = lo + RNG;
    int stride = (gridDim.x >> 3) * 256;
    for (int e = kg * 256 + threadIdx.x; e < NE; e += stride) {
        int d = dst[e];
        if (d >= lo && d < hi) {
            int p = atomicAdd(&off[d], 1);
            csr[p] = src[e];
        }
    }
    // post-fill: off[d] == end of row d; row d = [off[d-1], off[d]), off[-1]=0
}

// ---------------- hw1 = [x | pos] @ W1  (80 -> 64), tiled GEMM, fp16 out ---
__global__ __launch_bounds__(256) void k_hw1(const float* __restrict__ x,
                                             const float* __restrict__ pos,
                                             const float* __restrict__ W1,
                                             __half* __restrict__ hw1) {
    __shared__ float sh[TM * 80];   // [node][feat 0..79]
    __shared__ float sw[80 * 64];   // [k][j]
    int tid = threadIdx.x;
    for (int t = tid; t < 80 * 64; t += 256) sw[t] = W1[t];
    int nb = blockIdx.x * TM;
    for (int i = tid; i < TM * 64; i += 256) {       // x part (coalesced)
        int node = i >> 6, ch = i & 63;
        int g = nb + node;
        sh[node * 80 + ch] = (g < NN) ? x[g * 64 + ch] : 0.0f;
    }
    for (int i = tid; i < TM * 16; i += 256) {       // pos part (coalesced)
        int node = i >> 4, ch = i & 15;
        int g = nb + node;
        sh[node * 80 + 64 + ch] = (g < NN) ? pos[g * 16 + ch] : 0.0f;
    }
    __syncthreads();
    int j  = (tid & 15) * 4;        // output channel base
    int nl = (tid >> 4) * 4;        // local node base
    float a00=0,a01=0,a02=0,a03=0, a10=0,a11=0,a12=0,a13=0;
    float a20=0,a21=0,a22=0,a23=0, a30=0,a31=0,a32=0,a33=0;
#pragma unroll 4
    for (int k = 0; k < 80; ++k) {
        float4 wv = *(const float4*)&sw[k * 64 + j];
        float h0 = sh[(nl + 0) * 80 + k];
        float h1 = sh[(nl + 1) * 80 + k];
        float h2 = sh[(nl + 2) * 80 + k];
        float h3 = sh[(nl + 3) * 80 + k];
        a00 += h0 * wv.x; a01 += h0 * wv.y; a02 += h0 * wv.z; a03 += h0 * wv.w;
        a10 += h1 * wv.x; a11 += h1 * wv.y; a12 += h1 * wv.z; a13 += h1 * wv.w;
        a20 += h2 * wv.x; a21 += h2 * wv.y; a22 += h2 * wv.z; a23 += h2 * wv.w;
        a30 += h3 * wv.x; a31 += h3 * wv.y; a32 += h3 * wv.z; a33 += h3 * wv.w;
    }
    int g0 = nb + nl;
    union { __half2 h2v[2]; float2 f2; } u;
#define STORE_ROW(r, b0, b1, b2, b3)                                          \
    if (g0 + r < NN) {                                                        \
        u.h2v[0] = __floats2half2_rn(b0, b1);                                 \
        u.h2v[1] = __floats2half2_rn(b2, b3);                                 \
        *(float2*)&hw1[(g0 + r) * 64 + j] = u.f2;                             \
    }
    STORE_ROW(0, a00, a01, a02, a03)
    STORE_ROW(1, a10, a11, a12, a13)
    STORE_ROW(2, a20, a21, a22, a23)
    STORE_ROW(3, a30, a31, a32, a33)
#undef STORE_ROW
}

// ---------------- fused layer-1 gather + ReLU + W2 transform ----------------
// h2[d][c] = relu(b1[c] + sum_e hw1[s]*dinv[s]*dinv[d] + hw1[d]*dinv[d]^2)
// hw2[d][j] = sum_k h2[d][k] * W2[k][j]   (fp16 out)
// hw1 is fp16: 128 B/edge gather (R5 fp32 version fetched 280 MB from HBM/LLC).
// All shuffles execute with wave-uniform trip counts (full exec).
__global__ __launch_bounds__(256) void k_gather1_fused(const int* __restrict__ off,
                                                       const int* __restrict__ csr,
                                                       const float* __restrict__ dinv,
                                                       const __half* __restrict__ hw,
                                                       const float* __restrict__ b1,
                                                       const float* __restrict__ W2,
                                                       __half* __restrict__ hw2) {
    __shared__ float w[64 * 32];
    for (int t = threadIdx.x; t < 64 * 32; t += 256) w[t] = W2[t];
    __syncthreads();
    int lane = threadIdx.x & 63;
    int wave = threadIdx.x >> 6;
    int d = blockIdx.x * 4 + wave;             // grid = NN/4 exactly
    int start = (d == 0) ? 0 : off[d - 1];
    int end = off[d];
    float dd = dinv[d];
    float acc0 = 0.0f, acc1 = 0.0f;
    for (int base = start; base < end; base += 64) {
        int idx = base + lane;
        int sv = 0; float dn = 0.0f;
        if (idx < end) { sv = csr[idx]; dn = dinv[sv]; }
        int n = min(64, end - base);
        int jj = 0;
        for (; jj + 1 < n; jj += 2) {          // uniform: jj, n wave-uniform
            int   s0 = __shfl(sv, jj, 64);
            float n0 = __shfl(dn, jj, 64) * dd;
            int   s1 = __shfl(sv, jj + 1, 64);
            float n1 = __shfl(dn, jj + 1, 64) * dd;
            acc0 += __half2float(hw[s0 * 64 + lane]) * n0;
            acc1 += __half2float(hw[s1 * 64 + lane]) * n1;
        }
        if (jj < n) {                           // uniform branch, full exec
            int   s0 = __shfl(sv, jj, 64);
            float n0 = __shfl(dn, jj, 64) * dd;
            acc0 += __half2float(hw[s0 * 64 + lane]) * n0;
        }
    }
    float v = fmaxf(b1[lane] + (acc0 + acc1 + __half2float(hw[d * 64 + lane]) * dd * dd), 0.0f);
    // in-wave h2 @ W2: lane L handles out channel j=L&31, k-range [base2, base2+32)
    int j = lane & 31;
    int base2 = (lane >> 5) << 5;              // 0 for lanes 0-31, 32 for 32-63
    float acc = 0.0f;
#pragma unroll 8
    for (int k = 0; k < 32; ++k)
        acc += __shfl(v, base2 + k, 64) * w[(base2 + k) * 32 + j];
    acc += __shfl(acc, lane ^ 32, 64);         // combine k-halves
    if (lane < 32) hw2[d * 32 + j] = __float2half_rn(acc);
}

// ---------------- layer-2 gather (C=32, 2 edges/iter), fp16 source ---------
// z[d][j] = b2[j] + sum_e hw2[s]*dinv[s]*dinv[d] + hw2[d]*dinv[d]^2
// Uniform even bound nceil keeps both 32-lane halves in lockstep (full exec);
// the padding iteration shuffles from lane n (valid, holds sv=0/dn=0) -> +0.
__global__ __launch_bounds__(256) void k_gather2(const int* __restrict__ off,
                                                 const int* __restrict__ csr,
                                                 const float* __restrict__ dinv,
                                                 const __half* __restrict__ hw,
                                                 const float* __restrict__ b2,
                                                 float* __restrict__ outz) {
    int lane = threadIdx.x & 63;
    int half = lane >> 5;
    int j = lane & 31;
    int wave = threadIdx.x >> 6;
    int d = blockIdx.x * 4 + wave;             // grid = NN/4 exactly
    int start = (d == 0) ? 0 : off[d - 1];
    int end = off[d];
    float dd = dinv[d];
    float acc = 0.0f;
    for (int base = start; base < end; base += 64) {
        int idx = base + lane;
        int sv = 0; float dn = 0.0f;
        if (idx < end) { sv = csr[idx]; dn = dinv[sv]; }
        int n = min(64, end - base);
        int nceil = (n + 1) & ~1;              // uniform trip count both halves
        for (int jj = half; jj < nceil; jj += 2) {
            int   s = __shfl(sv, jj, 64);      // jj==n pad: dn=0 -> adds 0
            float nm = __shfl(dn, jj, 64) * dd;
            acc += __half2float(hw[s * 32 + j]) * nm;
        }
    }
    acc += __shfl(acc, lane ^ 32, 64);         // combine halves (full exec)
    if (half == 0)
        outz[d * 32 + j] = b2[j] + (acc + __half2float(hw[d * 32 + j]) * dd * dd);
}

// ---------------- link prediction head ----------------
__global__ __launch_bounds__(256) void k_linkpred(const int* __restrict__ sidx,
                                                  const int* __restrict__ didx,
                                                  const float* __restrict__ z,
                                                  const float* __restrict__ Wl,
                                                  const float* __restrict__ bl,
                                                  float* __restrict__ pred) {
    int t = blockIdx.x * blockDim.x + threadIdx.x;
    int lane = t & 63;
    int e = t >> 6;
    if (e >= NEL) return;                      // wave-uniform (e = t>>6)
    float wv = Wl[lane];
    int node = (lane < 32) ? sidx[e] : didx[e];
    float v = z[node * 32 + (lane & 31)] * wv;
#pragma unroll
    for (int off = 32; off > 0; off >>= 1) v += __shfl_down(v, off, 64);
    if (lane == 0) pred[e] = v + bl[0];
}

extern "C" void kernel_launch(void* const* d_in, const int* in_sizes, int n_in,
                              void* d_out, int out_size, void* d_ws, size_t ws_size,
                              hipStream_t stream) {
    const float* x    = (const float*)d_in[0];
    const float* pos  = (const float*)d_in[1];
    const float* W1   = (const float*)d_in[2];
    const float* b1   = (const float*)d_in[3];
    const float* W2   = (const float*)d_in[4];
    const float* b2   = (const float*)d_in[5];
    const float* Wl   = (const float*)d_in[6];
    const float* bl   = (const float*)d_in[7];
    const int*   ei   = (const int*)d_in[8];   // [2, NE]
    const int*   eli  = (const int*)d_in[9];   // [2, NEL]
    const int* src  = ei;
    const int* dst  = ei + NE;
    const int* lsrc = eli;
    const int* ldst = eli + NEL;

    float* out_z    = (float*)d_out;            // [NN, 32]
    float* out_pred = (float*)d_out + NN * 32;  // [NEL]

    // workspace: dinv[NN]f | off[NN]i | bsum[NB]i | ebsum[NB]i | csr[NE]i |
    //            hw1[NN*64]half | hw2[NN*32]half     ~= 26.4 MB total
    float*  dinv  = (float*)d_ws;
    int*    off   = (int*)(dinv + NN);
    int*    bsum  = off + NN;
    int*    ebsum = bsum + NB;
    int*    csr   = ebsum + NB;
    __half* hw1   = (__half*)(csr + NE);
    __half* hw2   = hw1 + NN * 64;

    // 1) CSR build + dinv (hist/fill XCD-partitioned: grid = 8 groups x 256)
    k_zero<<<(NN + 255) / 256, 256, 0, stream>>>(off);
    k_hist<<<2048, 256, 0, stream>>>(dst, off);
    k_dinv<<<(NN + 255) / 256, 256, 0, stream>>>(off, dinv);
    k_bsum<<<NB, 256, 0, stream>>>(off, bsum);
    k_bscan<<<1, 512, 0, stream>>>(bsum, ebsum);
    k_offsets<<<NB, 256, 0, stream>>>(off, ebsum);
    k_fill<<<2048, 256, 0, stream>>>(src, dst, off, csr);

    // 2) hw1 = [x|pos] @ W1 (fp16 out), tiled GEMM
    k_hw1<<<(NN + TM - 1) / TM, 256, 0, stream>>>(x, pos, W1, hw1);

    // 3) fused: layer-1 gather + bias + relu + (@W2) -> hw2 (fp16)
    k_gather1_fused<<<NN / 4, 256, 0, stream>>>(off, csr, dinv, hw1, b1, W2, hw2);

    // 4) layer-2 gather + bias -> z (fp32 out)
    k_gather2<<<NN / 4, 256, 0, stream>>>(off, csr, dinv, hw2, b2, out_z);

    // 5) link prediction
    k_linkpred<<<(NEL * 64 + 255) / 256, 256, 0, stream>>>(lsrc, ldst, out_z, Wl, bl, out_pred);
}

// Round 8
// 449.565 us; speedup vs baseline: 2.0166x; 1.0376x over previous
//
#include <hip/hip_runtime.h>
#include <hip/hip_fp16.h>

#define NN 100000     // num nodes
#define NE 1600000    // num edges
#define NEL 200000    // link-pred edges
#define NB 391        // (NN+255)/256 scan blocks
#define TM 64         // nodes per block in k_hw1
#define NGRP 8        // XCD partitions for CSR build
#define RNG (NN / NGRP)   // 12500 dst-nodes per partition

// ---------------- CSR build ----------------
__global__ void k_zero(int* __restrict__ c) {
    int i = blockIdx.x * blockDim.x + threadIdx.x;
    if (i < NN) c[i] = 0;
}

// Partitioned histogram: group g = blockIdx&7 (XCD swizzle heuristic) counts
// only dst in [g*RNG,(g+1)*RNG) -> atomics stay in one XCD's L2 slice.
__global__ __launch_bounds__(256) void k_hist(const int* __restrict__ dst,
                                              int* __restrict__ c) {
    int g  = blockIdx.x & 7;
    int kg = blockIdx.x >> 3;
    int lo = g * RNG, hi = lo + RNG;
    int stride = (gridDim.x >> 3) * 256;
    for (int e = kg * 256 + threadIdx.x; e < NE; e += stride) {
        int d = dst[e];
        if (d >= lo && d < hi) atomicAdd(&c[d], 1);
    }
}

__global__ void k_dinv(const int* __restrict__ c, float* __restrict__ dinv) {
    int i = blockIdx.x * blockDim.x + threadIdx.x;
    if (i < NN) dinv[i] = rsqrtf((float)(c[i] + 1));   // +1 self-loop
}

__global__ void k_bsum(const int* __restrict__ c, int* __restrict__ bsum) {
    __shared__ int s[256];
    int t = threadIdx.x, i = blockIdx.x * 256 + t;
    s[t] = (i < NN) ? c[i] : 0;
    __syncthreads();
    for (int st = 128; st > 0; st >>= 1) {
        if (t < st) s[t] += s[t + st];
        __syncthreads();
    }
    if (t == 0) bsum[blockIdx.x] = s[0];
}

__global__ void k_bscan(const int* __restrict__ bsum, int* __restrict__ ebsum) {
    __shared__ int s[512];
    int t = threadIdx.x;
    int v = (t < NB) ? bsum[t] : 0;
    s[t] = v;
    __syncthreads();
    for (int st = 1; st < 512; st <<= 1) {
        int tmp = (t >= st) ? s[t - st] : 0;
        __syncthreads();
        s[t] += tmp;
        __syncthreads();
    }
    if (t < NB) ebsum[t] = s[t] - v;   // exclusive
}

__global__ void k_offsets(int* __restrict__ c, const int* __restrict__ ebsum) {
    __shared__ int s[256];
    int t = threadIdx.x, i = blockIdx.x * 256 + t;
    int v = (i < NN) ? c[i] : 0;
    s[t] = v;
    __syncthreads();
    for (int st = 1; st < 256; st <<= 1) {
        int tmp = (t >= st) ? s[t - st] : 0;
        __syncthreads();
        s[t] += tmp;
        __syncthreads();
    }
    if (i < NN) c[i] = ebsum[blockIdx.x] + s[t] - v;   // exclusive offsets (in place)
}

// Partitioned fill (see R5: unpartitioned version wrote 105 MB for 6.4 MB csr).
__global__ __launch_bounds__(256) void k_fill(const int* __restrict__ src,
                                              const int* __restrict__ dst,
                                              int* __restrict__ off,
                                              int* __restrict__ csr) {
    int g  = blockIdx.x & 7;
    int kg = blockIdx.x >> 3;
    int lo = g * RNG, hi = lo + RNG;
    int stride = (gridDim.x >> 3) * 256;
    for (int e = kg * 256 + threadIdx.x; e < NE; e += stride) {
        int d = dst[e];
        if (d >= lo && d < hi) {
            int p = atomicAdd(&off[d], 1);
            csr[p] = src[e];
        }
    }
    // post-fill: off[d] == end of row d; row d = [off[d-1], off[d]), off[-1]=0
}

// ---------------- hw1 = [x | pos] @ W1  (80 -> 64), tiled GEMM, fp16 out ---
__global__ __launch_bounds__(256) void k_hw1(const float* __restrict__ x,
                                             const float* __restrict__ pos,
                                             const float* __restrict__ W1,
                                             __half* __restrict__ hw1) {
    __shared__ float sh[TM * 80];   // [node][feat 0..79]
    __shared__ float sw[80 * 64];   // [k][j]
    int tid = threadIdx.x;
    for (int t = tid; t < 80 * 64; t += 256) sw[t] = W1[t];
    int nb = blockIdx.x * TM;
    for (int i = tid; i < TM * 64; i += 256) {       // x part (coalesced)
        int node = i >> 6, ch = i & 63;
        int g = nb + node;
        sh[node * 80 + ch] = (g < NN) ? x[g * 64 + ch] : 0.0f;
    }
    for (int i = tid; i < TM * 16; i += 256) {       // pos part (coalesced)
        int node = i >> 4, ch = i & 15;
        int g = nb + node;
        sh[node * 80 + 64 + ch] = (g < NN) ? pos[g * 16 + ch] : 0.0f;
    }
    __syncthreads();
    int j  = (tid & 15) * 4;        // output channel base
    int nl = (tid >> 4) * 4;        // local node base
    float a00=0,a01=0,a02=0,a03=0, a10=0,a11=0,a12=0,a13=0;
    float a20=0,a21=0,a22=0,a23=0, a30=0,a31=0,a32=0,a33=0;
#pragma unroll 4
    for (int k = 0; k < 80; ++k) {
        float4 wv = *(const float4*)&sw[k * 64 + j];
        float h0 = sh[(nl + 0) * 80 + k];
        float h1 = sh[(nl + 1) * 80 + k];
        float h2 = sh[(nl + 2) * 80 + k];
        float h3 = sh[(nl + 3) * 80 + k];
        a00 += h0 * wv.x; a01 += h0 * wv.y; a02 += h0 * wv.z; a03 += h0 * wv.w;
        a10 += h1 * wv.x; a11 += h1 * wv.y; a12 += h1 * wv.z; a13 += h1 * wv.w;
        a20 += h2 * wv.x; a21 += h2 * wv.y; a22 += h2 * wv.z; a23 += h2 * wv.w;
        a30 += h3 * wv.x; a31 += h3 * wv.y; a32 += h3 * wv.z; a33 += h3 * wv.w;
    }
    int g0 = nb + nl;
    union { __half2 h2v[2]; float2 f2; } u;
#define STORE_ROW(r, b0, b1, b2, b3)                                          \
    if (g0 + r < NN) {                                                        \
        u.h2v[0] = __floats2half2_rn(b0, b1);                                 \
        u.h2v[1] = __floats2half2_rn(b2, b3);                                 \
        *(float2*)&hw1[(g0 + r) * 64 + j] = u.f2;                             \
    }
    STORE_ROW(0, a00, a01, a02, a03)
    STORE_ROW(1, a10, a11, a12, a13)
    STORE_ROW(2, a20, a21, a22, a23)
    STORE_ROW(3, a30, a31, a32, a33)
#undef STORE_ROW
}

// ---------------- fused layer-1 gather + ReLU + W2 transform ----------------
// h2[d][c] = relu(b1[c] + sum_e hw1[s]*dinv[s]*dinv[d] + hw1[d]*dinv[d]^2)
// hw2[d][j] = sum_k h2[d][k] * W2[k][j]   (fp16 out)
// R6 post-mortem: latency/MLP-bound (halving bytes left dur unchanged).
// -> 4 independent accumulators = 4 outstanding gathers per wave (was 2).
// All shuffles execute with wave-uniform trip counts (full exec).
__global__ __launch_bounds__(256) void k_gather1_fused(const int* __restrict__ off,
                                                       const int* __restrict__ csr,
                                                       const float* __restrict__ dinv,
                                                       const __half* __restrict__ hw,
                                                       const float* __restrict__ b1,
                                                       const float* __restrict__ W2,
                                                       __half* __restrict__ hw2) {
    __shared__ float w[64 * 32];
    for (int t = threadIdx.x; t < 64 * 32; t += 256) w[t] = W2[t];
    __syncthreads();
    int lane = threadIdx.x & 63;
    int wave = threadIdx.x >> 6;
    int d = blockIdx.x * 4 + wave;             // grid = NN/4 exactly
    int start = (d == 0) ? 0 : off[d - 1];
    int end = off[d];
    float dd = dinv[d];
    float hself = __half2float(hw[d * 64 + lane]);   // hoisted: overlaps loop
    float acc0 = 0.0f, acc1 = 0.0f, acc2 = 0.0f, acc3 = 0.0f;
    for (int base = start; base < end; base += 64) {
        int idx = base + lane;
        int sv = 0; float dn = 0.0f;
        if (idx < end) { sv = csr[idx]; dn = dinv[sv]; }
        int n = min(64, end - base);
        int jj = 0;
        for (; jj + 3 < n; jj += 4) {          // 4 outstanding gathers
            int   s0 = __shfl(sv, jj,     64);
            float n0 = __shfl(dn, jj,     64) * dd;
            int   s1 = __shfl(sv, jj + 1, 64);
            float n1 = __shfl(dn, jj + 1, 64) * dd;
            int   s2 = __shfl(sv, jj + 2, 64);
            float n2 = __shfl(dn, jj + 2, 64) * dd;
            int   s3 = __shfl(sv, jj + 3, 64);
            float n3 = __shfl(dn, jj + 3, 64) * dd;
            acc0 += __half2float(hw[s0 * 64 + lane]) * n0;
            acc1 += __half2float(hw[s1 * 64 + lane]) * n1;
            acc2 += __half2float(hw[s2 * 64 + lane]) * n2;
            acc3 += __half2float(hw[s3 * 64 + lane]) * n3;
        }
        for (; jj + 1 < n; jj += 2) {          // uniform remainder (pairs)
            int   s0 = __shfl(sv, jj,     64);
            float n0 = __shfl(dn, jj,     64) * dd;
            int   s1 = __shfl(sv, jj + 1, 64);
            float n1 = __shfl(dn, jj + 1, 64) * dd;
            acc0 += __half2float(hw[s0 * 64 + lane]) * n0;
            acc1 += __half2float(hw[s1 * 64 + lane]) * n1;
        }
        if (jj < n) {                           // uniform branch, full exec
            int   s0 = __shfl(sv, jj, 64);
            float n0 = __shfl(dn, jj, 64) * dd;
            acc0 += __half2float(hw[s0 * 64 + lane]) * n0;
        }
    }
    float v = fmaxf(b1[lane] + ((acc0 + acc1) + (acc2 + acc3) + hself * dd * dd), 0.0f);
    // in-wave h2 @ W2: lane L handles out channel j=L&31, k-range [base2, base2+32)
    int j = lane & 31;
    int base2 = (lane >> 5) << 5;              // 0 for lanes 0-31, 32 for 32-63
    float acc = 0.0f;
#pragma unroll 8
    for (int k = 0; k < 32; ++k)
        acc += __shfl(v, base2 + k, 64) * w[(base2 + k) * 32 + j];
    acc += __shfl(acc, lane ^ 32, 64);         // combine k-halves
    if (lane < 32) hw2[d * 32 + j] = __float2half_rn(acc);
}

// ---------------- layer-2 gather (C=32), 4 outstanding loads ----------------
// z[d][j] = b2[j] + sum_e hw2[s]*dinv[s]*dinv[d] + hw2[d]*dinv[d]^2
// Half h handles edges h, h+2, h+4... ; 2 accumulators per half = 4
// outstanding per wave. Uniform bound nceil4 (multiple of 4) keeps both
// halves in lockstep; pad lanes jj in [n, nceil4) are <= 63 and hold
// sv=0/dn=0 -> contribute 0 (same trick as the R3 fix).
__global__ __launch_bounds__(256) void k_gather2(const int* __restrict__ off,
                                                 const int* __restrict__ csr,
                                                 const float* __restrict__ dinv,
                                                 const __half* __restrict__ hw,
                                                 const float* __restrict__ b2,
                                                 float* __restrict__ outz) {
    int lane = threadIdx.x & 63;
    int half = lane >> 5;
    int j = lane & 31;
    int wave = threadIdx.x >> 6;
    int d = blockIdx.x * 4 + wave;             // grid = NN/4 exactly
    int start = (d == 0) ? 0 : off[d - 1];
    int end = off[d];
    float dd = dinv[d];
    float hself = __half2float(hw[d * 32 + j]);      // hoisted
    float accA = 0.0f, accB = 0.0f;
    for (int base = start; base < end; base += 64) {
        int idx = base + lane;
        int sv = 0; float dn = 0.0f;
        if (idx < end) { sv = csr[idx]; dn = dinv[sv]; }
        int n = min(64, end - base);
        int nceil4 = (n + 3) & ~3;             // uniform, multiple of 4, <= 64
        for (int jj = half; jj < nceil4; jj += 4) {
            int   sA = __shfl(sv, jj,     64); // pads read valid zero lanes
            float nA = __shfl(dn, jj,     64) * dd;
            int   sB = __shfl(sv, jj + 2, 64);
            float nB = __shfl(dn, jj + 2, 64) * dd;
            accA += __half2float(hw[sA * 32 + j]) * nA;
            accB += __half2float(hw[sB * 32 + j]) * nB;
        }
    }
    float acc = accA + accB;
    acc += __shfl(acc, lane ^ 32, 64);         // combine halves (full exec)
    if (half == 0)
        outz[d * 32 + j] = b2[j] + (acc + hself * dd * dd);
}

// ---------------- link prediction head ----------------
__global__ __launch_bounds__(256) void k_linkpred(const int* __restrict__ sidx,
                                                  const int* __restrict__ didx,
                                                  const float* __restrict__ z,
                                                  const float* __restrict__ Wl,
                                                  const float* __restrict__ bl,
                                                  float* __restrict__ pred) {
    int t = blockIdx.x * blockDim.x + threadIdx.x;
    int lane = t & 63;
    int e = t >> 6;
    if (e >= NEL) return;                      // wave-uniform (e = t>>6)
    float wv = Wl[lane];
    int node = (lane < 32) ? sidx[e] : didx[e];
    float v = z[node * 32 + (lane & 31)] * wv;
#pragma unroll
    for (int off = 32; off > 0; off >>= 1) v += __shfl_down(v, off, 64);
    if (lane == 0) pred[e] = v + bl[0];
}

extern "C" void kernel_launch(void* const* d_in, const int* in_sizes, int n_in,
                              void* d_out, int out_size, void* d_ws, size_t ws_size,
                              hipStream_t stream) {
    const float* x    = (const float*)d_in[0];
    const float* pos  = (const float*)d_in[1];
    const float* W1   = (const float*)d_in[2];
    const float* b1   = (const float*)d_in[3];
    const float* W2   = (const float*)d_in[4];
    const float* b2   = (const float*)d_in[5];
    const float* Wl   = (const float*)d_in[6];
    const float* bl   = (const float*)d_in[7];
    const int*   ei   = (const int*)d_in[8];   // [2, NE]
    const int*   eli  = (const int*)d_in[9];   // [2, NEL]
    const int* src  = ei;
    const int* dst  = ei + NE;
    const int* lsrc = eli;
    const int* ldst = eli + NEL;

    float* out_z    = (float*)d_out;            // [NN, 32]
    float* out_pred = (float*)d_out + NN * 32;  // [NEL]

    // workspace: dinv[NN]f | off[NN]i | bsum[NB]i | ebsum[NB]i | csr[NE]i |
    //            hw1[NN*64]half | hw2[NN*32]half     ~= 26.4 MB total
    float*  dinv  = (float*)d_ws;
    int*    off   = (int*)(dinv + NN);
    int*    bsum  = off + NN;
    int*    ebsum = bsum + NB;
    int*    csr   = ebsum + NB;
    __half* hw1   = (__half*)(csr + NE);
    __half* hw2   = hw1 + NN * 64;

    // 1) CSR build + dinv (hist/fill XCD-partitioned: grid = 8 groups x 256)
    k_zero<<<(NN + 255) / 256, 256, 0, stream>>>(off);
    k_hist<<<2048, 256, 0, stream>>>(dst, off);
    k_dinv<<<(NN + 255) / 256, 256, 0, stream>>>(off, dinv);
    k_bsum<<<NB, 256, 0, stream>>>(off, bsum);
    k_bscan<<<1, 512, 0, stream>>>(bsum, ebsum);
    k_offsets<<<NB, 256, 0, stream>>>(off, ebsum);
    k_fill<<<2048, 256, 0, stream>>>(src, dst, off, csr);

    // 2) hw1 = [x|pos] @ W1 (fp16 out), tiled GEMM
    k_hw1<<<(NN + TM - 1) / TM, 256, 0, stream>>>(x, pos, W1, hw1);

    // 3) fused: layer-1 gather + bias + relu + (@W2) -> hw2 (fp16)
    k_gather1_fused<<<NN / 4, 256, 0, stream>>>(off, csr, dinv, hw1, b1, W2, hw2);

    // 4) layer-2 gather + bias -> z (fp32 out)
    k_gather2<<<NN / 4, 256, 0, stream>>>(off, csr, dinv, hw2, b2, out_z);

    // 5) link prediction
    k_linkpred<<<(NEL * 64 + 255) / 256, 256, 0, stream>>>(lsrc, ldst, out_z, Wl, bl, out_pred);
}